// Round 1
// baseline (89.882 us; speedup 1.0000x reference)
//
#include <hip/hip_runtime.h>
#include <math.h>

// ParabolicPool1DFast: B=32, C=64, L=4096, KS=7, STRIDE=2, HALF=3.
//
// Reference semantics (verified by hand):
//   dil[b,c,l] = max_{j=0..6} f[b,c,l+j-3] + h[c,j],  h[c,j] = -(j-3)^2/(4*t[c])
//   (taps outside [0,L) are -inf)
//   flat = dil.reshape(-1)   (C-order over (B,C,L))
//   out[b,c,i] = flat[b + c + 2*i],  i in [0,2048)
//
// Max flat index = 31 + 63 + 2*2047 = 4188  ->  only dil[0,0,0:4096] and
// dil[0,1,0:93] are ever consumed. The kernel builds that 4189-entry table in
// LDS per block, then streams the 16.78 MB output (pure write-bound).
//
// LDS table is split even/odd so the gather base+2*i becomes a stride-1 read
// (2 lanes/bank = free) instead of stride-2 (4 lanes/bank, 1.58x).

#define THREADS   256
#define NBLOCKS   512
#define PER_BLOCK 8192            // 4194304 / 512
#define NFLAT     4189

__global__ __launch_bounds__(THREADS) void ParabolicPool1DFast_kernel(
    const float* __restrict__ f,   // [32,64,4096] but only rows (0,0) and (0,1) used
    const float* __restrict__ t,   // [64], only t[0], t[1] used
    float* __restrict__ out)       // [32,64,2048] flat
{
    __shared__ float ev[2096];     // flat[2m]
    __shared__ float od[2096];     // flat[2m+1]

    const int tid = threadIdx.x;
    const float inv4t0 = 0.25f / t[0];
    const float inv4t1 = 0.25f / t[1];

    // Phase 1: build the dilation table for flat[0..4189)
    for (int q = tid; q < NFLAT; q += THREADS) {
        const int c = q >> 12;            // 0 for q<4096, else 1
        const int l = q & 4095;
        const float* frow = f + (c << 12);
        const float inv4t = c ? inv4t1 : inv4t0;
        float best = -INFINITY;
#pragma unroll
        for (int j = 0; j < 7; ++j) {
            const int z = j - 3;
            const int idx = l + z;
            if (idx >= 0 && idx < 4096) {
                best = fmaxf(best, frow[idx] - (float)(z * z) * inv4t);
            }
        }
        if (q & 1) od[q >> 1] = best;
        else       ev[q >> 1] = best;
    }
    __syncthreads();

    // Phase 2: stream the output. Each block owns a contiguous 8192-float chunk.
    const int base_o = (int)blockIdx.x * PER_BLOCK;
#pragma unroll
    for (int k = 0; k < PER_BLOCK / THREADS; ++k) {
        const int o    = base_o + k * THREADS + tid;
        const int i    = o & 2047;                 // column within row
        const int r    = o >> 11;                  // row = bi*64 + ci
        const int base = (r >> 6) + (r & 63);      // bi + ci  (wave-uniform)
        // flat[base + 2*i]: even base -> ev[base/2 + i], odd -> od[base/2 + i]
        const float* tab = (base & 1) ? od : ev;
        out[o] = tab[(base >> 1) + i];
    }
}

extern "C" void kernel_launch(void* const* d_in, const int* in_sizes, int n_in,
                              void* d_out, int out_size, void* d_ws, size_t ws_size,
                              hipStream_t stream) {
    const float* f = (const float*)d_in[0];   // [32,64,4096] fp32
    const float* t = (const float*)d_in[1];   // [64] fp32
    float* out = (float*)d_out;               // 4194304 fp32
    ParabolicPool1DFast_kernel<<<NBLOCKS, THREADS, 0, stream>>>(f, t, out);
}

// Round 3
// 79.338 us; speedup vs baseline: 1.1329x; 1.1329x over previous
//
#include <hip/hip_runtime.h>
#include <math.h>

// ParabolicPool1DFast: B=32, C=64, L=4096, KS=7, STRIDE=2, HALF=3.
//
// Reference semantics (verified absmax 0.0 in round 1):
//   dil[b,c,l] = max_{z=-3..3} f[b,c,l+z] - z^2/(4*t[c])   (-inf outside [0,L))
//   out[b,c,i] = dil_flat[(b + c) + 2*i]    (faithful as_strided gather)
// Max flat index = 31+63+2*2047 = 4188 -> only dil[0,0,0:4096] and
// dil[0,1,0:93) are consumed (4189 entries). Each block rebuilds that table
// in LDS (even/odd split -> the stride-2 gather is a stride-1 read), then
// streams one 2048-float output row (grid = 2048 = number of rows).
//
// Round-3 fix: round 2 crashed on an OOB write — PER_TH was left at 32 when
// the grid went 512->2048 (4x overrun, 67 MB into a 16.78 MB buffer).
// Correct per-thread output is 8 floats. Phase 2 restructured: one row per
// block makes base = bi+ci block-uniform (scalar select of ev/od), so phase 2
// is 2x ds_read_b128 + 2x global_store_dwordx4 per thread.

#define THREADS 256
#define NBLOCKS 2048            // == number of output rows (32*64)
#define NFLAT   4189

__global__ __launch_bounds__(THREADS) void ParabolicPool1DFast_kernel(
    const float* __restrict__ f,   // [32,64,4096]; only rows (0,0),(0,1) used
    const float* __restrict__ t,   // [64]; only t[0], t[1] used
    float* __restrict__ out)       // [32,64,2048] flat
{
    __shared__ __align__(16) float ev[2096];   // dil_flat[2m]
    __shared__ __align__(16) float od[2096];   // dil_flat[2m+1]

    const int tid = threadIdx.x;
    const float a0 = 0.25f / t[0];
    const float a1 = 0.25f / t[1];

    // ---- Phase 1a: dil_flat[16*tid .. 16*tid+16) from f row 0 ----
    {
        const float4* f4 = (const float4*)f;   // row 0 = f4[0..1024)
        float w[24];                           // f[16*tid-4 .. 16*tid+20)
        const int b0 = 4 * tid - 1;
#pragma unroll
        for (int v = 0; v < 6; ++v) {
            const int fi = b0 + v;
            const int fic = fi < 0 ? 0 : (fi > 1023 ? 1023 : fi);
            float4 x = f4[fic];
            if (fi < 0 || fi > 1023) {         // border: -inf padding
                x.x = -INFINITY; x.y = -INFINITY; x.z = -INFINITY; x.w = -INFINITY;
            }
            w[4*v+0] = x.x; w[4*v+1] = x.y; w[4*v+2] = x.z; w[4*v+3] = x.w;
        }
        const float c1 = a0, c2 = 4.0f * a0, c3 = 9.0f * a0;
        float ve[8], vo[8];
#pragma unroll
        for (int p = 0; p < 16; ++p) {
            // dil_flat[16*tid+p]: taps w[p+1..p+7], center w[p+4]
            const float m1 = fmaxf(w[p+3], w[p+5]);
            const float m2 = fmaxf(w[p+2], w[p+6]);
            const float m3 = fmaxf(w[p+1], w[p+7]);
            const float val = fmaxf(fmaxf(w[p+4], m1 - c1),
                                    fmaxf(m2 - c2, m3 - c3));
            if (p & 1) vo[p >> 1] = val;
            else       ve[p >> 1] = val;
        }
        ((float4*)ev)[2*tid]     = make_float4(ve[0], ve[1], ve[2], ve[3]);
        ((float4*)ev)[2*tid + 1] = make_float4(ve[4], ve[5], ve[6], ve[7]);
        ((float4*)od)[2*tid]     = make_float4(vo[0], vo[1], vo[2], vo[3]);
        ((float4*)od)[2*tid + 1] = make_float4(vo[4], vo[5], vo[6], vo[7]);
    }

    // ---- Phase 1b: dil_flat[4096 .. 4189) from f row 1 ----
    if (tid < NFLAT - 4096) {                  // 93 threads
        const float* frow = f + 4096;
        float best = -INFINITY;
#pragma unroll
        for (int j = 0; j < 7; ++j) {
            const int z = j - 3;
            const int idx = tid + z;
            if (idx >= 0 && idx < 4096)
                best = fmaxf(best, frow[idx] - (float)(z * z) * a1);
        }
        const int q = 4096 + tid;
        if (q & 1) od[q >> 1] = best;
        else       ev[q >> 1] = best;
    }
    __syncthreads();

    // ---- Phase 2: one output row per block ----
    const int r    = (int)blockIdx.x;          // row = bi*64 + ci
    const int base = (r >> 6) + (r & 63);      // bi + ci  (block-uniform)
    const float* tab  = (base & 1) ? od : ev;  // scalar select
    const int    toff = base >> 1;
    float* orow = out + (r << 11);
    // out[r,i] = dil_flat[base + 2i] = tab[toff + i];  512 float4 per row
#pragma unroll
    for (int k = 0; k < 2; ++k) {
        const int i = (k * THREADS + tid) * 4; // 0..2047, float4-aligned
        const float4 v = make_float4(tab[toff + i],     tab[toff + i + 1],
                                     tab[toff + i + 2], tab[toff + i + 3]);
        *(float4*)(orow + i) = v;
    }
}

extern "C" void kernel_launch(void* const* d_in, const int* in_sizes, int n_in,
                              void* d_out, int out_size, void* d_ws, size_t ws_size,
                              hipStream_t stream) {
    const float* f = (const float*)d_in[0];   // [32,64,4096] fp32
    const float* t = (const float*)d_in[1];   // [64] fp32
    float* out = (float*)d_out;               // 4194304 fp32
    ParabolicPool1DFast_kernel<<<NBLOCKS, THREADS, 0, stream>>>(f, t, out);
}